// Round 8
// baseline (366.397 us; speedup 1.0000x reference)
//
#include <hip/hip_runtime.h>

// feat: [N=8, C=2048, H=64, W=64] fp32
// proto: [K=21, C=2048] fp32
// out:  [N=8, K=21, H=64, W=64] fp32 = relu(cosine_sim over C)
//
// Memory-bound target: 256 MiB feat read-once -> ~43 us @ 6.3 TB/s;
// VALU floor ~19 us (no fp32 MFMA on CDNA4); VMEM-issue ~21 us.
// Geometry (forced: 32768 px / 128 px-per-block = 256 blocks = 1/CU):
//   block = 1024 thr = 16 waves; all waves share the same 128 pixels
//   (64 lanes x float2); wave w owns C-slice [w*128, (w+1)*128).
// Inner loop processes c in QUADS: one float4 proto load per k per 4
// c-steps (25 VMEM vs 176 VALU per iter -> VMEM issue not binding).
// #pragma unroll 1 caps register pressure (~85 VGPR < 128 cap); 1-deep
// feat prefetch (~1400 cyc wall) hides the ~900 cyc HBM miss latency.
// Tail: parallel per-wave-per-k LDS reduction (2 chunks, 5 barriers).

#define CDIM 2048
#define HW   4096
#define KNUM 21
#define EPS  1e-8f

__global__ __launch_bounds__(1024, 4)
void feat_proto_cos_kernel(const float* __restrict__ feat,
                           const float* __restrict__ proto,
                           float* __restrict__ out) {
    const int tid  = threadIdx.x;
    const int lane = tid & 63;
    // wave id forced into SGPR so per-wave proto addressing is provably uniform
    const int wv   = __builtin_amdgcn_readfirstlane(tid >> 6);   // 0..15
    const int b    = blockIdx.x;          // 0..255
    const int n    = b >> 5;              // image index
    const int hwb  = (b & 31) << 7;       // base pixel in HW plane
    const int px   = hwb + lane * 2;      // this lane's pixel pair

    __shared__ float  pnorm[KNUM];
    __shared__ float2 fnormS[64];         // feat norms for the 128 pixels
    __shared__ float2 red[16][1024];      // 128 KB reduction buffer (1 blk/CU)

    // ---- prototype norms (redundant per block; proto is L2-resident) ----
    for (int k = wv; k < KNUM; k += 16) {
        float s = 0.f;
        for (int i = lane; i < CDIM; i += 64) {
            float p = proto[k * CDIM + i];
            s += p * p;
        }
        #pragma unroll
        for (int off = 32; off > 0; off >>= 1) s += __shfl_down(s, off);
        if (lane == 0) pnorm[k] = sqrtf(s);
    }

    // ---- main streaming loop over this wave's C slice ----
    const int c0 = wv * 128;
    const float* fp = feat + ((size_t)n * CDIM + c0) * HW + px;
    const float* pp = proto + c0;          // pp[k*CDIM + c]: wave-uniform address

    float2 acc[KNUM];
    #pragma unroll
    for (int k = 0; k < KNUM; ++k) acc[k] = make_float2(0.f, 0.f);
    float2 nrm = make_float2(0.f, 0.f);

    // software-pipelined feat quad (prefetch depth 1 iteration = 4 c-steps)
    float2 f0 = *(const float2*)(fp + (size_t)0 * HW);
    float2 f1 = *(const float2*)(fp + (size_t)1 * HW);
    float2 f2 = *(const float2*)(fp + (size_t)2 * HW);
    float2 f3 = *(const float2*)(fp + (size_t)3 * HW);

    #pragma unroll 1
    for (int cc = 0; cc < 128; cc += 4) {
        // prefetch next quad (clamped: last iter re-reads cc=120..123, harmless)
        const int cn = (cc + 4 < 128) ? (cc + 4) : 120;
        float2 g0 = *(const float2*)(fp + (size_t)(cn + 0) * HW);
        float2 g1 = *(const float2*)(fp + (size_t)(cn + 1) * HW);
        float2 g2 = *(const float2*)(fp + (size_t)(cn + 2) * HW);
        float2 g3 = *(const float2*)(fp + (size_t)(cn + 3) * HW);

        nrm.x += f0.x * f0.x;  nrm.y += f0.y * f0.y;
        nrm.x += f1.x * f1.x;  nrm.y += f1.y * f1.y;
        nrm.x += f2.x * f2.x;  nrm.y += f2.y * f2.y;
        nrm.x += f3.x * f3.x;  nrm.y += f3.y * f3.y;

        #pragma unroll   // acc[k] must stay register-indexed (rule #20)
        for (int k = 0; k < KNUM; ++k) {
            // proto[k][c0+cc .. c0+cc+3]: ONE 16-B uniform load per k
            float4 p = *(const float4*)(pp + k * CDIM + cc);
            acc[k].x += f0.x * p.x;  acc[k].y += f0.y * p.x;
            acc[k].x += f1.x * p.y;  acc[k].y += f1.y * p.y;
            acc[k].x += f2.x * p.z;  acc[k].y += f2.y * p.z;
            acc[k].x += f3.x * p.w;  acc[k].y += f3.y * p.w;
        }
        f0 = g0; f1 = g1; f2 = g2; f3 = g3;
    }

    // ---- feat-norm cross-wave reduction ----
    red[0][tid] = nrm;
    __syncthreads();
    if (wv == 0) {
        float2 s = red[0][lane];
        #pragma unroll
        for (int w = 1; w < 16; ++w) {
            float2 t = red[0][w * 64 + lane];
            s.x += t.x; s.y += t.y;
        }
        fnormS[lane] = make_float2(sqrtf(s.x), sqrtf(s.y));
    }
    __syncthreads();
    const float2 fn = fnormS[lane];

    // ---- dot reduction chunk 1: k = 0..15, one k per wave ----
    #pragma unroll
    for (int kk = 0; kk < 16; ++kk) red[kk][tid] = acc[kk];
    __syncthreads();
    {
        const int k = wv;                  // 0..15
        float2 s = red[k][lane];
        #pragma unroll
        for (int w = 1; w < 16; ++w) {
            float2 t = red[k][w * 64 + lane];
            s.x += t.x; s.y += t.y;
        }
        const float pn = pnorm[k];
        float ox = fmaxf(s.x / fmaxf(fn.x * pn, EPS), 0.f);
        float oy = fmaxf(s.y / fmaxf(fn.y * pn, EPS), 0.f);
        *(float2*)(out + ((size_t)n * KNUM + k) * HW + px) = make_float2(ox, oy);
    }
    __syncthreads();

    // ---- chunk 2: k = 16..20, waves 0..4 ----
    #pragma unroll
    for (int kk = 0; kk < 5; ++kk) red[kk][tid] = acc[16 + kk];
    __syncthreads();
    if (wv < 5) {
        const int k = 16 + wv;
        float2 s = red[wv][lane];
        #pragma unroll
        for (int w = 1; w < 16; ++w) {
            float2 t = red[wv][w * 64 + lane];
            s.x += t.x; s.y += t.y;
        }
        const float pn = pnorm[k];
        float ox = fmaxf(s.x / fmaxf(fn.x * pn, EPS), 0.f);
        float oy = fmaxf(s.y / fmaxf(fn.y * pn, EPS), 0.f);
        *(float2*)(out + ((size_t)n * KNUM + k) * HW + px) = make_float2(ox, oy);
    }
}

extern "C" void kernel_launch(void* const* d_in, const int* in_sizes, int n_in,
                              void* d_out, int out_size, void* d_ws, size_t ws_size,
                              hipStream_t stream) {
    const float* feat  = (const float*)d_in[0];
    const float* proto = (const float*)d_in[1];
    // d_in[2] = class_numbers (fixed 21, baked into KNUM)
    float* out = (float*)d_out;

    feat_proto_cos_kernel<<<256, 1024, 0, stream>>>(feat, proto, out);
}

// Round 9
// 365.377 us; speedup vs baseline: 1.0028x; 1.0028x over previous
//
#include <hip/hip_runtime.h>

// feat: [N=8, C=2048, H=64, W=64] fp32
// proto: [K=21, C=2048] fp32
// out:  [N=8, K=21, H=64, W=64] fp32 = relu(cosine_sim over C)
//
// HBM floor ~43 us (256 MiB feat read-once @ 6.3 TB/s); VALU ~19 us;
// VMEM-issue ~21 us. Geometry forced: 32768 px / 128 px-per-block =
// 256 blocks = 1 block/CU; 16 waves share the block's 128 pixels
// (64 lanes x float2); wave w owns C-slice [w*128, (w+1)*128).
//
// R8 experiment: PREFETCH DEPTH 2 (three quad-buffers f/g/h, 8 float2
// loads = 64 B/lane in flight) to discriminate latency-bound (H1: total
// drops ~50 us) vs already-at-floor (H2: total flat). Proto loads are
// wave-uniform float4 (scalar s_load_dwordx4, L2-resident). Tail:
// parallel per-wave-per-k LDS reduction (2 chunks, 5 barriers).

#define CDIM 2048
#define HW   4096
#define KNUM 21
#define EPS  1e-8f

__global__ __launch_bounds__(1024, 4)
void feat_proto_cos_kernel(const float* __restrict__ feat,
                           const float* __restrict__ proto,
                           float* __restrict__ out) {
    const int tid  = threadIdx.x;
    const int lane = tid & 63;
    // wave id forced into SGPR so per-wave proto addressing is provably uniform
    const int wv   = __builtin_amdgcn_readfirstlane(tid >> 6);   // 0..15
    const int b    = blockIdx.x;          // 0..255
    const int n    = b >> 5;              // image index
    const int hwb  = (b & 31) << 7;       // base pixel in HW plane
    const int px   = hwb + lane * 2;      // this lane's pixel pair

    __shared__ float  pnorm[KNUM];
    __shared__ float2 fnormS[64];         // feat norms for the 128 pixels
    __shared__ float2 red[16][1024];      // 128 KB reduction buffer (1 blk/CU)

    // ---- prototype norms (redundant per block; proto is L2-resident) ----
    for (int k = wv; k < KNUM; k += 16) {
        float s = 0.f;
        for (int i = lane; i < CDIM; i += 64) {
            float p = proto[k * CDIM + i];
            s += p * p;
        }
        #pragma unroll
        for (int off = 32; off > 0; off >>= 1) s += __shfl_down(s, off);
        if (lane == 0) pnorm[k] = sqrtf(s);
    }

    // ---- main streaming loop over this wave's C slice ----
    const int c0 = wv * 128;
    const float* fp = feat + ((size_t)n * CDIM + c0) * HW + px;
    const float* pp = proto + c0;          // pp[k*CDIM + c]: wave-uniform address

    float2 acc[KNUM];
    #pragma unroll
    for (int k = 0; k < KNUM; ++k) acc[k] = make_float2(0.f, 0.f);
    float2 nrm = make_float2(0.f, 0.f);

    // depth-2 software pipeline: f = quad(cc), g = quad(cc+4), h = quad(cc+8)
    float2 f0 = *(const float2*)(fp + (size_t)0 * HW);
    float2 f1 = *(const float2*)(fp + (size_t)1 * HW);
    float2 f2 = *(const float2*)(fp + (size_t)2 * HW);
    float2 f3 = *(const float2*)(fp + (size_t)3 * HW);
    float2 g0 = *(const float2*)(fp + (size_t)4 * HW);
    float2 g1 = *(const float2*)(fp + (size_t)5 * HW);
    float2 g2 = *(const float2*)(fp + (size_t)6 * HW);
    float2 g3 = *(const float2*)(fp + (size_t)7 * HW);

    #pragma unroll 1
    for (int cc = 0; cc < 128; cc += 4) {
        // prefetch quad cc+8 (clamped at the tail: re-reads quad 112, harmless)
        const int cn = (cc + 8 < 128) ? (cc + 8) : 112;
        float2 h0 = *(const float2*)(fp + (size_t)(cn + 0) * HW);
        float2 h1 = *(const float2*)(fp + (size_t)(cn + 1) * HW);
        float2 h2 = *(const float2*)(fp + (size_t)(cn + 2) * HW);
        float2 h3 = *(const float2*)(fp + (size_t)(cn + 3) * HW);

        nrm.x += f0.x * f0.x;  nrm.y += f0.y * f0.y;
        nrm.x += f1.x * f1.x;  nrm.y += f1.y * f1.y;
        nrm.x += f2.x * f2.x;  nrm.y += f2.y * f2.y;
        nrm.x += f3.x * f3.x;  nrm.y += f3.y * f3.y;

        #pragma unroll   // acc[k] must stay register-indexed (rule #20)
        for (int k = 0; k < KNUM; ++k) {
            // proto[k][c0+cc .. c0+cc+3]: ONE 16-B uniform load per k
            float4 p = *(const float4*)(pp + k * CDIM + cc);
            acc[k].x += f0.x * p.x;  acc[k].y += f0.y * p.x;
            acc[k].x += f1.x * p.y;  acc[k].y += f1.y * p.y;
            acc[k].x += f2.x * p.z;  acc[k].y += f2.y * p.z;
            acc[k].x += f3.x * p.w;  acc[k].y += f3.y * p.w;
        }
        f0 = g0; f1 = g1; f2 = g2; f3 = g3;
        g0 = h0; g1 = h1; g2 = h2; g3 = h3;
    }

    // ---- feat-norm cross-wave reduction ----
    red[0][tid] = nrm;
    __syncthreads();
    if (wv == 0) {
        float2 s = red[0][lane];
        #pragma unroll
        for (int w = 1; w < 16; ++w) {
            float2 t = red[0][w * 64 + lane];
            s.x += t.x; s.y += t.y;
        }
        fnormS[lane] = make_float2(sqrtf(s.x), sqrtf(s.y));
    }
    __syncthreads();
    const float2 fn = fnormS[lane];

    // ---- dot reduction chunk 1: k = 0..15, one k per wave ----
    #pragma unroll
    for (int kk = 0; kk < 16; ++kk) red[kk][tid] = acc[kk];
    __syncthreads();
    {
        const int k = wv;                  // 0..15
        float2 s = red[k][lane];
        #pragma unroll
        for (int w = 1; w < 16; ++w) {
            float2 t = red[k][w * 64 + lane];
            s.x += t.x; s.y += t.y;
        }
        const float pn = pnorm[k];
        float ox = fmaxf(s.x / fmaxf(fn.x * pn, EPS), 0.f);
        float oy = fmaxf(s.y / fmaxf(fn.y * pn, EPS), 0.f);
        *(float2*)(out + ((size_t)n * KNUM + k) * HW + px) = make_float2(ox, oy);
    }
    __syncthreads();

    // ---- chunk 2: k = 16..20, waves 0..4 ----
    #pragma unroll
    for (int kk = 0; kk < 5; ++kk) red[kk][tid] = acc[16 + kk];
    __syncthreads();
    if (wv < 5) {
        const int k = 16 + wv;
        float2 s = red[wv][lane];
        #pragma unroll
        for (int w = 1; w < 16; ++w) {
            float2 t = red[wv][w * 64 + lane];
            s.x += t.x; s.y += t.y;
        }
        const float pn = pnorm[k];
        float ox = fmaxf(s.x / fmaxf(fn.x * pn, EPS), 0.f);
        float oy = fmaxf(s.y / fmaxf(fn.y * pn, EPS), 0.f);
        *(float2*)(out + ((size_t)n * KNUM + k) * HW + px) = make_float2(ox, oy);
    }
}

extern "C" void kernel_launch(void* const* d_in, const int* in_sizes, int n_in,
                              void* d_out, int out_size, void* d_ws, size_t ws_size,
                              hipStream_t stream) {
    const float* feat  = (const float*)d_in[0];
    const float* proto = (const float*)d_in[1];
    // d_in[2] = class_numbers (fixed 21, baked into KNUM)
    float* out = (float*)d_out;

    feat_proto_cos_kernel<<<256, 1024, 0, stream>>>(feat, proto, out);
}